// Round 3
// baseline (102.245 us; speedup 1.0000x reference)
//
#include <hip/hip_runtime.h>

#define N_PIX 4096
#define N_CH 256
#define KSEL 16
#define CCAP 64

__device__ __forceinline__ unsigned f2key(float f) {
  unsigned u = __float_as_uint(f);
  return u ^ ((unsigned)((int)u >> 31) | 0x80000000u);
}
__device__ __forceinline__ float key2f(unsigned k) {
  unsigned u = (k & 0x80000000u) ? (k ^ 0x80000000u) : ~k;
  return __uint_as_float(u);
}
__device__ __forceinline__ unsigned umaxu(unsigned a, unsigned b) { return a > b ? a : b; }

// ---- full descending bitonic sort across the 64 lanes of a wave ----
__device__ __forceinline__ unsigned bitonic64_desc_u32(unsigned v, int lane) {
#pragma unroll
  for (int k = 2; k <= 64; k <<= 1) {
#pragma unroll
    for (int j = k >> 1; j >= 1; j >>= 1) {
      unsigned o = (unsigned)__shfl_xor((int)v, j, 64);
      const bool lower = (lane & j) == 0;
      const bool asc = (lane & k) != 0;
      v = (lower == asc) ? (v < o ? v : o) : (v > o ? v : o);
    }
  }
  return v;
}
__device__ __forceinline__ unsigned long long bitonic64_desc_u64(unsigned long long v, int lane) {
#pragma unroll
  for (int k = 2; k <= 64; k <<= 1) {
#pragma unroll
    for (int j = k >> 1; j >= 1; j >>= 1) {
      unsigned lo = (unsigned)__shfl_xor((int)(unsigned)v, j, 64);
      unsigned hi = (unsigned)__shfl_xor((int)(unsigned)(v >> 32), j, 64);
      unsigned long long o = ((unsigned long long)hi << 32) | lo;
      const bool lower = (lane & j) == 0;
      const bool asc = (lane & k) != 0;
      v = (lower == asc) ? (v < o ? v : o) : (v > o ? v : o);
    }
  }
  return v;
}

// feat [B, C, N] -> feat_t [B, N, C], 32x32 LDS tile transpose
__global__ void transpose_feat_kernel(const float* __restrict__ feat,
                                      float* __restrict__ feat_t) {
  __shared__ float tile[32][33];
  const int b = blockIdx.z;
  const int n0 = blockIdx.x * 32;
  const int c0 = blockIdx.y * 32;
  const int tx = threadIdx.x, ty = threadIdx.y;
  const float* src = feat + (size_t)b * N_CH * N_PIX;
  float* dst = feat_t + (size_t)b * N_PIX * N_CH;
#pragma unroll
  for (int j = 0; j < 32; j += 8)
    tile[ty + j][tx] = src[(size_t)(c0 + ty + j) * N_PIX + n0 + tx];
  __syncthreads();
#pragma unroll
  for (int j = 0; j < 32; j += 8)
    dst[(size_t)(n0 + ty + j) * N_CH + c0 + tx] = tile[tx][ty + j];
}

// Block = 256 threads, 4 consecutive rows (sequential). Per row:
//   sampled-threshold select: T = 16th largest of the 256 thread-maxima
//   (every top-16 element is >= T; expected candidates ~ 17-25),
//   candidate list in LDS, one 64-lane bitonic sort on (key,idx) composites
//   -> exact top-16 with top_k tie semantics (value desc, index asc).
template <bool FT>
__global__ __launch_bounds__(256) void topk_sel_kernel(
    const float* __restrict__ aff, const float* __restrict__ feat,
    float* __restrict__ out) {
  __shared__ unsigned s_m[64];                 // 4 waves x top-16 thread-maxima
  __shared__ unsigned long long s_cand[CCAP];  // candidate composites
  __shared__ float s_wt[KSEL];                 // normalized softmax weights
  __shared__ unsigned s_j[KSEL];               // winner indices
  __shared__ unsigned s_nc;

  const int tid = threadIdx.x;
  const int lane = tid & 63;
  const int w = tid >> 6;
  const int rg = blockIdx.x;        // 0..2047 (4 rows each)
  const int b = rg >> 10;
  const int i0 = (rg & 1023) * 4;

  float accs[4];

#pragma unroll
  for (int r = 0; r < 4; ++r) {
    const int row = rg * 4 + r;
    const float4* arow = (const float4*)(aff + (size_t)row * N_PIX);

    // coalesced load: 16 values/thread, sortable keys in registers
    unsigned key[16];
    unsigned m = 0;
#pragma unroll
    for (int q = 0; q < 4; ++q) {
      float4 v = arow[q * 256 + tid];
      unsigned k0 = f2key(v.x), k1 = f2key(v.y), k2 = f2key(v.z), k3 = f2key(v.w);
      key[q * 4 + 0] = k0; key[q * 4 + 1] = k1;
      key[q * 4 + 2] = k2; key[q * 4 + 3] = k3;
      m = umaxu(m, umaxu(umaxu(k0, k1), umaxu(k2, k3)));
    }

    // per-wave sort of thread-maxima; publish wave's top-16
    unsigned sm = bitonic64_desc_u32(m, lane);
    if (lane < 16) s_m[w * 16 + lane] = sm;
    if (tid == 0) s_nc = 0;
    __syncthreads();  // B1

    // cross-wave: T = 16th largest of the 256 thread-maxima (redundant per wave)
    unsigned x = bitonic64_desc_u32(s_m[lane], lane);
    const unsigned T = (unsigned)__shfl((int)x, 15, 64);

    // enumerate candidates >= T into LDS (expected ~17-25 per row)
#pragma unroll
    for (int q = 0; q < 4; ++q) {
#pragma unroll
      for (int c = 0; c < 4; ++c) {
        unsigned k = key[q * 4 + c];
        if (k >= T) {
          unsigned pos = atomicAdd(&s_nc, 1u);
          unsigned idx = (unsigned)(q * 1024 + tid * 4 + c);
          if (pos < CCAP)
            s_cand[pos] = ((unsigned long long)k << 12) | (4095u - idx);
        }
      }
    }
    __syncthreads();  // B2

    // exact top-16 of candidates (value desc, index asc), softmax
    unsigned nc = s_nc; if (nc > CCAP) nc = CCAP;
    unsigned long long cv = (lane < (int)nc) ? s_cand[lane] : 0ull;
    cv = bitonic64_desc_u64(cv, lane);
    float v = key2f((unsigned)(cv >> 12));
    float vmax = __shfl(v, 0, 64);
    float ev = (lane < KSEL) ? __expf(v - vmax) : 0.f;
    float rs = ev;
#pragma unroll
    for (int o2 = 1; o2 < 64; o2 <<= 1) rs += __shfl_xor(rs, o2, 64);
    if (w == 0 && lane < KSEL) {
      s_wt[lane] = ev / rs;
      s_j[lane] = 4095u - (unsigned)(cv & 0xFFFu);
    }
    __syncthreads();  // B3

    // weighted gather-sum: thread = channel
    float a = 0.f;
    if (FT) {
      const float* fb = feat + (((size_t)b << 12)) * N_CH + tid;  // [B,N,C]
#pragma unroll
      for (int k = 0; k < KSEL; ++k)
        a = fmaf(s_wt[k], fb[(size_t)s_j[k] * N_CH], a);
    } else {
      const float* fb = feat + ((size_t)(b * N_CH + tid)) * N_PIX;  // [B,C,N]
#pragma unroll
      for (int k = 0; k < KSEL; ++k)
        a = fmaf(s_wt[k], fb[s_j[k]], a);
    }
    accs[r] = a;
    __syncthreads();  // B4: protect LDS reuse in next row iteration
  }

  // out[b, c, i0..i0+3] as one float4 (full-line write-combining)
  float4 o; o.x = accs[0]; o.y = accs[1]; o.z = accs[2]; o.w = accs[3];
  *(float4*)(out + ((size_t)(b * N_CH + tid)) * N_PIX + i0) = o;
}

extern "C" void kernel_launch(void* const* d_in, const int* in_sizes, int n_in,
                              void* d_out, int out_size, void* d_ws, size_t ws_size,
                              hipStream_t stream) {
  const float* aff = (const float*)d_in[0];
  const float* feat = (const float*)d_in[1];
  float* out = (float*)d_out;
  const size_t feat_t_bytes = (size_t)2 * N_PIX * N_CH * sizeof(float);
  if (ws_size >= feat_t_bytes) {
    float* feat_t = (float*)d_ws;
    dim3 tb(32, 8, 1);
    dim3 tg(N_PIX / 32, N_CH / 32, 2);
    transpose_feat_kernel<<<tg, tb, 0, stream>>>(feat, feat_t);
    topk_sel_kernel<true><<<2048, 256, 0, stream>>>(aff, feat_t, out);
  } else {
    topk_sel_kernel<false><<<2048, 256, 0, stream>>>(aff, feat, out);
  }
}

// Round 4
// 62.491 us; speedup vs baseline: 1.6362x; 1.6362x over previous
//
#include <hip/hip_runtime.h>

#define N_PIX 4096
#define N_CH 256
#define KSEL 16
#define WCAP 32  // per-wave candidate cap (expected ~18)

__device__ __forceinline__ unsigned f2key(float f) {
  unsigned u = __float_as_uint(f);
  return u ^ ((unsigned)((int)u >> 31) | 0x80000000u);
}
__device__ __forceinline__ float key2f(unsigned k) {
  unsigned u = (k & 0x80000000u) ? (k ^ 0x80000000u) : ~k;
  return __uint_as_float(u);
}

// feat [B, C, N] -> feat_t [B, N, C], 32x32 LDS tile transpose
__global__ void transpose_feat_kernel(const float* __restrict__ feat,
                                      float* __restrict__ feat_t) {
  __shared__ float tile[32][33];
  const int b = blockIdx.z;
  const int n0 = blockIdx.x * 32;
  const int c0 = blockIdx.y * 32;
  const int tx = threadIdx.x, ty = threadIdx.y;
  const float* src = feat + (size_t)b * N_CH * N_PIX;
  float* dst = feat_t + (size_t)b * N_PIX * N_CH;
#pragma unroll
  for (int j = 0; j < 32; j += 8)
    tile[ty + j][tx] = src[(size_t)(c0 + ty + j) * N_PIX + n0 + tx];
  __syncthreads();
#pragma unroll
  for (int j = 0; j < 32; j += 8)
    dst[(size_t)(n0 + ty + j) * N_CH + c0 + tx] = tile[tx][ty + j];
}

// Block = 256 threads = 4 waves, 4 consecutive rows (sequential, prefetched).
// Selection is ballot-radix (VALU/SALU only): per-wave threshold from the 64
// thread-maxima -> candidate superset in LDS -> wave0 exact top-16 over <=128
// candidates. 2 barriers/row via parity-buffered LDS. No LDS atomics, no
// bitonic shfl chains.
template <bool FT>
__global__ __launch_bounds__(256) void topk_ballot_kernel(
    const float* __restrict__ aff, const float* __restrict__ feat,
    float* __restrict__ out) {
  __shared__ unsigned s_ck[2][4][WCAP];
  __shared__ unsigned s_cj[2][4][WCAP];
  __shared__ unsigned s_cn[2][4];
  __shared__ float s_wt[2][KSEL];
  __shared__ unsigned s_j[2][KSEL];

  const int tid = threadIdx.x;
  const int lane = tid & 63;
  const int w = tid >> 6;
  const int rg = blockIdx.x;      // 2048 groups of 4 rows
  const int b = rg >> 10;
  const int i0 = (rg & 1023) * 4;
  const unsigned long long lt = (1ull << lane) - 1ull;

  float accs[4];
  const float* aff_rg = aff + (size_t)rg * 4 * N_PIX;

  // prefetch row 0
  float4 pv[4];
#pragma unroll
  for (int q = 0; q < 4; ++q) pv[q] = ((const float4*)aff_rg)[q * 256 + tid];

  for (int r = 0; r < 4; ++r) {
    const int p = r & 1;

    // keys from prefetched values
    unsigned key[16];
#pragma unroll
    for (int q = 0; q < 4; ++q) {
      key[q * 4 + 0] = f2key(pv[q].x);
      key[q * 4 + 1] = f2key(pv[q].y);
      key[q * 4 + 2] = f2key(pv[q].z);
      key[q * 4 + 3] = f2key(pv[q].w);
    }
    // issue next row's loads now; they complete under this row's compute
    if (r < 3) {
      const float4* nxt = (const float4*)(aff_rg + (size_t)(r + 1) * N_PIX);
#pragma unroll
      for (int q = 0; q < 4; ++q) pv[q] = nxt[q * 256 + tid];
    }

    // thread max
    unsigned m = key[0];
#pragma unroll
    for (int e = 1; e < 16; ++e) m = key[e] > m ? key[e] : m;

    // ---- per-wave ballot-radix over the 64 thread-maxima -> threshold ----
    unsigned prefix = 0, need = KSEL;
    bool early = false;
    int bb = 31;
    for (; bb >= 0; --bb) {
      unsigned want = (prefix << 1) | 1u;
      unsigned cnt = (unsigned)__popcll(__ballot((m >> bb) == want));
      if (cnt >= need) {
        prefix = want;
        if (cnt == need) { early = true; break; }
      } else {
        need -= cnt;
        prefix <<= 1;
      }
    }
    unsigned thr = early ? (prefix << bb) : prefix;

    // ---- emit candidates >= thr (ballot-rank compaction, no atomics) ----
    unsigned base = 0;
#pragma unroll
    for (int e = 0; e < 16; ++e) {
      bool sel = key[e] >= thr;
      unsigned long long mk = __ballot(sel);
      if (sel) {
        unsigned pos = base + (unsigned)__popcll(mk & lt);
        if (pos < WCAP) {
          s_ck[p][w][pos] = key[e];
          s_cj[p][w][pos] = (unsigned)((e >> 2) * 1024 + tid * 4 + (e & 3));
        }
      }
      base += (unsigned)__popcll(mk);
    }
    // rare overflow: redo with the exact per-wave element threshold
    if (base > WCAP) {
      prefix = 0; need = KSEL; early = false;
      for (bb = 31; bb >= 0; --bb) {
        unsigned want = (prefix << 1) | 1u;
        unsigned cnt = 0;
#pragma unroll
        for (int e = 0; e < 16; ++e)
          cnt += (unsigned)__popcll(__ballot((key[e] >> bb) == want));
        if (cnt >= need) {
          prefix = want;
          if (cnt == need) { early = true; break; }
        } else {
          need -= cnt;
          prefix <<= 1;
        }
      }
      thr = early ? (prefix << bb) : prefix;
      base = 0;
#pragma unroll
      for (int e = 0; e < 16; ++e) {
        bool sel = key[e] >= thr;
        unsigned long long mk = __ballot(sel);
        if (sel) {
          unsigned pos = base + (unsigned)__popcll(mk & lt);
          if (pos < WCAP) {
            s_ck[p][w][pos] = key[e];
            s_cj[p][w][pos] = (unsigned)((e >> 2) * 1024 + tid * 4 + (e & 3));
          }
        }
        base += (unsigned)__popcll(mk);
      }
    }
    if (lane == 0) s_cn[p][w] = base < WCAP ? base : WCAP;

    __syncthreads();  // B1: candidates published

    // ---- wave 0: exact top-16 over <=128 candidates (2 slots/lane) ----
    if (w == 0) {
      const int sw = lane >> 4, sp = lane & 15;
      const unsigned nW = s_cn[p][sw];
      unsigned k0 = 0, j0 = 0, k1 = 0, j1 = 0;
      if ((unsigned)sp < nW) { k0 = s_ck[p][sw][sp]; j0 = s_cj[p][sw][sp]; }
      if ((unsigned)(sp + 16) < nW) { k1 = s_ck[p][sw][sp + 16]; j1 = s_cj[p][sw][sp + 16]; }

      unsigned mx = k0 > k1 ? k0 : k1;
#pragma unroll
      for (int off = 32; off; off >>= 1) {
        unsigned o = (unsigned)__shfl_xor((int)mx, off, 64);
        mx = o > mx ? o : mx;
      }
      const float vmax = key2f(mx);

      unsigned prefix2 = 0, need2 = KSEL;
      bool early2 = false;
      int b2 = 31;
      for (; b2 >= 0; --b2) {
        unsigned want = (prefix2 << 1) | 1u;
        unsigned cnt = (unsigned)__popcll(__ballot((k0 >> b2) == want)) +
                       (unsigned)__popcll(__ballot((k1 >> b2) == want));
        if (cnt >= need2) {
          prefix2 = want;
          if (cnt == need2) { early2 = true; break; }
        } else {
          need2 -= cnt;
          prefix2 <<= 1;
        }
      }

      bool w0, w1;
      if (early2) {
        const unsigned thr2 = prefix2 << b2;
        w0 = k0 >= thr2;
        w1 = k1 >= thr2;
      } else {
        const unsigned T = prefix2;  // exact 16th value; promote lowest-index ties
        w0 = k0 > T;
        w1 = k1 > T;
        bool t0 = (k0 == T), t1 = (k1 == T);
        for (unsigned q = 0; q < need2; ++q) {
          unsigned mi = 0xFFFFFFFFu;
          if (t0) mi = j0;
          if (t1 && j1 < mi) mi = j1;
#pragma unroll
          for (int off = 32; off; off >>= 1) {
            unsigned o = (unsigned)__shfl_xor((int)mi, off, 64);
            mi = o < mi ? o : mi;
          }
          if (t0 && j0 == mi) { w0 = true; t0 = false; }
          else if (t1 && j1 == mi) { w1 = true; t1 = false; }
        }
      }

      const float e0 = w0 ? __expf(key2f(k0) - vmax) : 0.f;
      const float e1 = w1 ? __expf(key2f(k1) - vmax) : 0.f;
      float s = e0 + e1;
#pragma unroll
      for (int off = 32; off; off >>= 1) s += __shfl_xor(s, off, 64);
      const float inv = 1.0f / s;

      const unsigned long long m0 = __ballot(w0);
      const unsigned long long m1 = __ballot(w1);
      const unsigned c0n = (unsigned)__popcll(m0);
      if (w0) {
        unsigned rk = (unsigned)__popcll(m0 & lt);
        s_wt[p][rk] = e0 * inv;
        s_j[p][rk] = j0;
      }
      if (w1) {
        unsigned rk = c0n + (unsigned)__popcll(m1 & lt);
        s_wt[p][rk] = e1 * inv;
        s_j[p][rk] = j1;
      }
    }
    __syncthreads();  // B2: weights published

    // ---- weighted gather-sum: thread = channel ----
    float a = 0.f;
    if (FT) {
      const float* fb = feat + ((size_t)b * N_PIX) * N_CH + tid;  // [B,N,C]
#pragma unroll
      for (int k = 0; k < KSEL; ++k)
        a = fmaf(s_wt[p][k], fb[(size_t)s_j[p][k] * N_CH], a);
    } else {
      const float* fb = feat + ((size_t)(b * N_CH + tid)) * N_PIX;  // [B,C,N]
#pragma unroll
      for (int k = 0; k < KSEL; ++k)
        a = fmaf(s_wt[p][k], fb[s_j[p][k]], a);
    }
    accs[r] = a;
    // no trailing barrier: next row uses the other parity buffers
  }

  // out[b, c, i0..i0+3] as one float4 per channel
  float4 o;
  o.x = accs[0]; o.y = accs[1]; o.z = accs[2]; o.w = accs[3];
  *(float4*)(out + ((size_t)(b * N_CH + tid)) * N_PIX + i0) = o;
}

extern "C" void kernel_launch(void* const* d_in, const int* in_sizes, int n_in,
                              void* d_out, int out_size, void* d_ws, size_t ws_size,
                              hipStream_t stream) {
  const float* aff = (const float*)d_in[0];
  const float* feat = (const float*)d_in[1];
  float* out = (float*)d_out;
  const size_t feat_t_bytes = (size_t)2 * N_PIX * N_CH * sizeof(float);
  if (ws_size >= feat_t_bytes) {
    float* feat_t = (float*)d_ws;
    dim3 tb(32, 8, 1);
    dim3 tg(N_PIX / 32, N_CH / 32, 2);
    transpose_feat_kernel<<<tg, tb, 0, stream>>>(feat, feat_t);
    topk_ballot_kernel<true><<<2048, 256, 0, stream>>>(aff, feat_t, out);
  } else {
    topk_ballot_kernel<false><<<2048, 256, 0, stream>>>(aff, feat, out);
  }
}

// Round 5
// 49.476 us; speedup vs baseline: 2.0665x; 1.2630x over previous
//
#include <hip/hip_runtime.h>

#define N_PIX 4096
#define N_CH 256
#define KSEL 16

__device__ __forceinline__ unsigned f2key(float f) {
  unsigned u = __float_as_uint(f);
  return u ^ ((unsigned)((int)u >> 31) | 0x80000000u);
}
__device__ __forceinline__ float key2f(unsigned k) {
  unsigned u = (k & 0x80000000u) ? (k ^ 0x80000000u) : ~k;
  return __uint_as_float(u);
}
__device__ __forceinline__ unsigned umax2(unsigned a, unsigned b) { return a > b ? a : b; }

// feat [B, C, N] -> feat_t [B, N, C], 32x32 LDS tile transpose
__global__ void transpose_feat_kernel(const float* __restrict__ feat,
                                      float* __restrict__ feat_t) {
  __shared__ float tile[32][33];
  const int b = blockIdx.z;
  const int n0 = blockIdx.x * 32;
  const int c0 = blockIdx.y * 32;
  const int tx = threadIdx.x, ty = threadIdx.y;
  const float* src = feat + (size_t)b * N_CH * N_PIX;
  float* dst = feat_t + (size_t)b * N_PIX * N_CH;
#pragma unroll
  for (int j = 0; j < 32; j += 8)
    tile[ty + j][tx] = src[(size_t)(c0 + ty + j) * N_PIX + n0 + tx];
  __syncthreads();
#pragma unroll
  for (int j = 0; j < 32; j += 8)
    dst[(size_t)(n0 + ty + j) * N_CH + c0 + tx] = tile[tx][ty + j];
}

// Block = 4 waves; EACH WAVE owns one full row (64 keys/lane, no spill thanks
// to __launch_bounds__(256,3) -> VGPR cap ~170). Selection per wave:
//   T1 = exact 16th-largest of the 64 lane-maxima (branchless 32-step
//        ballot-radix; pure VALU/SALU, no cross-wave traffic)
//   candidates >= T1 (superset of row top-16, E[count]~18-25) compacted by
//        ballot-rank into per-wave LDS (no atomics, no barriers)
//   T2 = exact 16th-largest candidate (second branchless ballot-radix,
//        one candidate per lane) + tie-by-lowest-index (top_k semantics)
// Softmax normalization deferred to the gather epilogue (no shfl reduce).
// One barrier total (output staging for full-line float4 stores).
template <bool FT>
__global__ __launch_bounds__(256, 3) void topk_wave_kernel(
    const float* __restrict__ aff, const float* __restrict__ feat,
    float* __restrict__ out) {
  __shared__ unsigned s_ck[4][64];
  __shared__ unsigned s_cj[4][64];
  __shared__ uint2 s_wj[4][KSEL];   // (exp(v-T2) bits, index)
  __shared__ float s_out[4][N_CH];

  const int tid = threadIdx.x;
  const int lane = tid & 63;
  const int w = tid >> 6;
  const int rg = blockIdx.x;        // 2048 blocks x 4 rows
  const int b = rg >> 10;
  const int i0 = (rg & 1023) * 4;
  const int row = rg * 4 + w;
  const unsigned long long lt = (1ull << lane) - 1ull;

  // ---- load whole row into the wave: 64 keys/lane, coalesced float4 ----
  const float4* arow = (const float4*)(aff + (size_t)row * N_PIX);
  unsigned key[64];
  unsigned m = 0;
#pragma unroll
  for (int q = 0; q < 16; ++q) {
    float4 v = arow[q * 64 + lane];
    unsigned k0 = f2key(v.x), k1 = f2key(v.y), k2 = f2key(v.z), k3 = f2key(v.w);
    key[4 * q + 0] = k0; key[4 * q + 1] = k1;
    key[4 * q + 2] = k2; key[4 * q + 3] = k3;
    m = umax2(m, umax2(umax2(k0, k1), umax2(k2, k3)));
  }

  // ---- stage 1: T1 = exact 16th-largest lane-max (branchless ballot-radix)
  unsigned p1 = 0, need1 = KSEL;
#pragma unroll
  for (int bit = 31; bit >= 0; --bit) {
    unsigned want = (p1 << 1) | 1u;
    unsigned cnt = (unsigned)__popcll(__ballot((m >> bit) == want));
    bool take = cnt >= need1;
    p1 = want - (take ? 0u : 1u);
    need1 = take ? need1 : need1 - cnt;
  }
  const unsigned T1 = p1;  // >=16 elements of the row are >= T1; superset holds

  // ---- enumerate candidates >= T1 via ballot-rank (no atomics) ----
  unsigned base = 0;
#pragma unroll
  for (int e = 0; e < 64; ++e) {
    bool sel = key[e] >= T1;
    unsigned long long mk = __ballot(sel);
    if (sel) {
      unsigned pos = base + (unsigned)__popcll(mk & lt);
      if (pos < 64) {
        s_ck[w][pos] = key[e];
        s_cj[w][pos] = (unsigned)((e >> 2) * 256 + lane * 4 + (e & 3));
      }
    }
    base += (unsigned)__popcll(mk);
  }

  if (__builtin_expect(base <= 64, 1)) {
    // ---- stage 2: exact top-16 among candidates (one per lane) ----
    unsigned cv = 0, cj = 0xFFFFFFFFu;
    if (lane < (int)base) { cv = s_ck[w][lane]; cj = s_cj[w][lane]; }
    unsigned p2 = 0, need2 = KSEL;
#pragma unroll
    for (int bit = 31; bit >= 0; --bit) {
      unsigned want = (p2 << 1) | 1u;
      unsigned cnt = (unsigned)__popcll(__ballot((cv >> bit) == want));
      bool take = cnt >= need2;
      p2 = want - (take ? 0u : 1u);
      need2 = take ? need2 : need2 - cnt;
    }
    const unsigned T2 = p2;  // exact 16th-largest value; need2 = #ties to take
    bool win = (cv > T2);
    bool eq = (cv == T2) && (lane < (int)base);
    unsigned long long eqm = __ballot(eq);
    if (need2 == (unsigned)__popcll(eqm)) {
      win = win || eq;  // all threshold-ties included (unique-value fast path)
    } else {
      // cold: lowest-index subset of the == T2 ties
      bool t = eq;
      for (unsigned q = 0; q < need2; ++q) {
        unsigned mi = t ? cj : 0xFFFFFFFFu;
#pragma unroll
        for (int off = 32; off; off >>= 1) {
          unsigned o = (unsigned)__shfl_xor((int)mi, off, 64);
          mi = o < mi ? o : mi;
        }
        if (t && cj == mi) { win = true; t = false; }
      }
    }
    unsigned long long wm = __ballot(win);
    if (win) {
      unsigned rk = (unsigned)__popcll(wm & lt);
      float ew = __expf(key2f(cv) - key2f(T2));
      s_wj[w][rk] = make_uint2(__float_as_uint(ew), cj);
    }
  } else {
    // ---- cold fallback (candidate overflow): exact radix over all keys ----
    unsigned p2 = 0, need2 = KSEL;
    for (int bit = 31; bit >= 0; --bit) {
      unsigned want = (p2 << 1) | 1u;
      unsigned cnt = 0;
#pragma unroll
      for (int e = 0; e < 64; ++e)
        cnt += (unsigned)__popcll(__ballot((key[e] >> bit) == want));
      bool take = cnt >= need2;
      p2 = want - (take ? 0u : 1u);
      need2 = take ? need2 : need2 - cnt;
    }
    const unsigned T2 = p2;
    unsigned rk = 0;
#pragma unroll
    for (int e = 0; e < 64; ++e) {
      bool sel = key[e] > T2;
      unsigned long long mk = __ballot(sel);
      if (sel) {
        unsigned pos = rk + (unsigned)__popcll(mk & lt);
        float ew = __expf(key2f(key[e]) - key2f(T2));
        s_wj[w][pos] = make_uint2(__float_as_uint(ew),
                                  (unsigned)((e >> 2) * 256 + lane * 4 + (e & 3)));
      }
      rk += (unsigned)__popcll(mk);
    }
    // need2 lowest-index ties == T2 (ew = 1.0)
    unsigned long long done = 0ull;
    for (unsigned q = 0; q < need2; ++q) {
      unsigned mi = 0xFFFFFFFFu;
#pragma unroll
      for (int e = 0; e < 64; ++e) {
        if (key[e] == T2 && !((done >> e) & 1ull)) {
          unsigned j = (unsigned)((e >> 2) * 256 + lane * 4 + (e & 3));
          if (j < mi) mi = j;
        }
      }
      unsigned gmi = mi;
#pragma unroll
      for (int off = 32; off; off >>= 1) {
        unsigned o = (unsigned)__shfl_xor((int)gmi, off, 64);
        gmi = o < gmi ? o : gmi;
      }
      if (mi == gmi && gmi != 0xFFFFFFFFu) {  // unique owner lane
        unsigned e = ((gmi >> 8) << 2) | (gmi & 3);
        done |= (1ull << e);
        s_wj[w][rk + q] = make_uint2(__float_as_uint(1.0f), gmi);
      }
    }
  }

  // ---- epilogue: read 16 (ew, j), sum, gather, normalize ----
  float ews[KSEL];
  unsigned js[KSEL];
  float ssum = 0.f;
#pragma unroll
  for (int k = 0; k < KSEL; ++k) {
    uint2 t = s_wj[w][k];           // same-wave LDS RAW: lgkmcnt, no barrier
    ews[k] = __uint_as_float(t.x);
    js[k] = t.y;
    ssum += ews[k];
  }
  const float inv = 1.0f / ssum;

  float ax = 0.f, ay = 0.f, az = 0.f, aw = 0.f;
  if (FT) {
    const float* fb = feat + (size_t)b * N_PIX * N_CH + lane * 4;  // [B,N,C]
#pragma unroll
    for (int k = 0; k < KSEL; ++k) {
      const float4 f = *(const float4*)(fb + (size_t)js[k] * N_CH);
      ax += ews[k] * f.x; ay += ews[k] * f.y;
      az += ews[k] * f.z; aw += ews[k] * f.w;
    }
  } else {
    const float* fb = feat + (size_t)b * N_CH * N_PIX;  // [B,C,N] fallback
    const int c0 = lane * 4;
#pragma unroll
    for (int k = 0; k < KSEL; ++k) {
      ax += ews[k] * fb[(size_t)(c0 + 0) * N_PIX + js[k]];
      ay += ews[k] * fb[(size_t)(c0 + 1) * N_PIX + js[k]];
      az += ews[k] * fb[(size_t)(c0 + 2) * N_PIX + js[k]];
      aw += ews[k] * fb[(size_t)(c0 + 3) * N_PIX + js[k]];
    }
  }
  float4 accv;
  accv.x = ax * inv; accv.y = ay * inv; accv.z = az * inv; accv.w = aw * inv;
  *(float4*)&s_out[w][lane * 4] = accv;

  __syncthreads();  // the only block barrier: assemble full-line output stores

  {
    const int c = tid;
    float4 o;
    o.x = s_out[0][c]; o.y = s_out[1][c]; o.z = s_out[2][c]; o.w = s_out[3][c];
    *(float4*)(out + ((size_t)(b * N_CH + c)) * N_PIX + i0) = o;
  }
}

extern "C" void kernel_launch(void* const* d_in, const int* in_sizes, int n_in,
                              void* d_out, int out_size, void* d_ws, size_t ws_size,
                              hipStream_t stream) {
  const float* aff = (const float*)d_in[0];
  const float* feat = (const float*)d_in[1];
  float* out = (float*)d_out;
  const size_t feat_t_bytes = (size_t)2 * N_PIX * N_CH * sizeof(float);
  if (ws_size >= feat_t_bytes) {
    float* feat_t = (float*)d_ws;
    dim3 tb(32, 8, 1);
    dim3 tg(N_PIX / 32, N_CH / 32, 2);
    transpose_feat_kernel<<<tg, tb, 0, stream>>>(feat, feat_t);
    topk_wave_kernel<true><<<2048, 256, 0, stream>>>(aff, feat_t, out);
  } else {
    topk_wave_kernel<false><<<2048, 256, 0, stream>>>(aff, feat, out);
  }
}